// Round 7
// baseline (1860.616 us; speedup 1.0000x reference)
//
#include <hip/hip_runtime.h>
#include <hip/hip_bf16.h>

#define B_ 2
#define S_ 2048
#define D_ 1024
#define N_ 16
#define R_ 64
#define NC 64          // number of scan chunks
#define CL 32          // chunk length  (NC*CL == S_)
#define BS_ (B_*S_)

typedef __attribute__((ext_vector_type(4))) float f32x4;
typedef __attribute__((ext_vector_type(8))) short bf16x8;
typedef __attribute__((ext_vector_type(8))) unsigned short u16x8;

__device__ __forceinline__ unsigned short f2b(float v) {
  unsigned u = __builtin_bit_cast(unsigned, v);
  unsigned r = ((u >> 16) & 1u) + 0x7FFFu;
  return (unsigned short)((u + r) >> 16);
}

__device__ __forceinline__ void gload_lds16(const void* g, void* l) {
  __builtin_amdgcn_global_load_lds(
      (const __attribute__((address_space(1))) unsigned int*)g,
      (__attribute__((address_space(3))) unsigned int*)l, 16, 0, 0);
}

// ---------------- fp32 -> bf16 casts (x + all weights) ----------------
// regions (fp32 element offsets, all multiples of 1024):
//  [0,       4194304) x     -> xb
//  [4194304, 4210688) W_B   -> WBC rows 0..15
//  [4210688, 4227072) W_C   -> WBC rows 16..31
//  [4227072, 4292608) W_dt  -> wdtb  [1024][64]
//  [4292608, 5341184) W_out -> wob   [1024][1024]
//  [5341184, 5406720) W_dtw -> TRANSPOSED to wdtwT [e][r]
__global__ __launch_bounds__(256) void k_castall(
    const float* __restrict__ x, const float* __restrict__ W_B,
    const float* __restrict__ W_C, const float* __restrict__ W_dt,
    const float* __restrict__ W_out, const float* __restrict__ W_dtw,
    unsigned short* __restrict__ xb, unsigned short* __restrict__ WBC,
    unsigned short* __restrict__ wdtb, unsigned short* __restrict__ wob,
    unsigned short* __restrict__ wdtwT) {
  int i = (blockIdx.x * 256 + threadIdx.x) * 4;   // grid covers 5406720 elems
  if (i < 5341184) {
    const float* s; unsigned short* d; int off;
    if (i < 4194304)      { s = x;     d = xb;          off = 0; }
    else if (i < 4210688) { s = W_B;   d = WBC;         off = 4194304; }
    else if (i < 4227072) { s = W_C;   d = WBC + 16384; off = 4210688; }
    else if (i < 4292608) { s = W_dt;  d = wdtb;        off = 4227072; }
    else                  { s = W_out; d = wob;         off = 4292608; }
    int j = i - off;
    float4 v = *(const float4*)&s[j];
    ushort4 o;
    o.x = f2b(v.x); o.y = f2b(v.y); o.z = f2b(v.z); o.w = f2b(v.w);
    *(ushort4*)&d[j] = o;
  } else {
    int j = i - 5341184;            // flat index into W_dtw [64][1024]
    int r = j >> 10, e = j & 1023;
    float4 v = *(const float4*)&W_dtw[j];
    wdtwT[(size_t)(e + 0) * 64 + r] = f2b(v.x);
    wdtwT[(size_t)(e + 1) * 64 + r] = f2b(v.y);
    wdtwT[(size_t)(e + 2) * 64 + r] = f2b(v.z);
    wdtwT[(size_t)(e + 3) * 64 + r] = f2b(v.w);
  }
}

// ---------------- W_eff = W_dt[1024,64] x W_dtw[64,1024] -> bf16 [d][e] ----------------
__global__ __launch_bounds__(256) void k_weff(
    const unsigned short* __restrict__ wdtb, const unsigned short* __restrict__ wdtwT,
    unsigned short* __restrict__ weff) {
  __shared__ __align__(16) unsigned short As[128 * 64];
  __shared__ __align__(16) unsigned short Bs[128 * 64];
  const int tid = threadIdx.x;
  const int lane = tid & 63, wid = tid >> 6;
  const int wr = wid >> 1, wc = wid & 1;
  const size_t row0 = (size_t)blockIdx.x * 128;   // d
  const size_t col0 = (size_t)blockIdx.y * 128;   // e
  f32x4 acc[4][4] = {};
  {
    const int r = tid >> 3, s = tid & 7;
    #pragma unroll
    for (int i = 0; i < 4; ++i) {
      const int row = i * 32 + r;
      const int gs = s ^ (row & 7);
      gload_lds16(wdtb + (row0 + row) * R_ + gs * 8, As + row * 64 + s * 8);
      gload_lds16(wdtwT + (col0 + row) * R_ + gs * 8, Bs + row * 64 + s * 8);
    }
  }
  __syncthreads();
  const int r = lane & 15, kg = lane >> 4;
  #pragma unroll
  for (int ks = 0; ks < 2; ++ks) {
    bf16x8 a[4], b[4];
    #pragma unroll
    for (int m = 0; m < 4; ++m) {
      const int arow = wr * 64 + m * 16 + r;
      a[m] = *(const bf16x8*)&As[arow * 64 + (((ks << 2) | kg) ^ (arow & 7)) * 8];
    }
    #pragma unroll
    for (int n = 0; n < 4; ++n) {
      const int brow = wc * 64 + n * 16 + r;
      b[n] = *(const bf16x8*)&Bs[brow * 64 + (((ks << 2) | kg) ^ (brow & 7)) * 8];
    }
    #pragma unroll
    for (int m = 0; m < 4; ++m)
      #pragma unroll
      for (int n = 0; n < 4; ++n)
        acc[m][n] = __builtin_amdgcn_mfma_f32_16x16x32_bf16(a[m], b[n], acc[m][n], 0, 0, 0);
  }
  const int cr = lane >> 4, cc = lane & 15;
  #pragma unroll
  for (int m = 0; m < 4; ++m)
    #pragma unroll
    for (int n = 0; n < 4; ++n)
      #pragma unroll
      for (int j = 0; j < 4; ++j)
        weff[(row0 + wr * 64 + m * 16 + cr * 4 + j) * D_ + col0 + wc * 64 + n * 16 + cc]
            = f2b(acc[m][n][j]);
}

// ---------------- shared staging helpers (k_out structure) ----------------
__device__ __forceinline__ void stage128x64(const unsigned short* __restrict__ g,
                                            size_t row0, int k0,
                                            unsigned short* lds, int tid) {
  const int r = tid >> 3, s = tid & 7;
  #pragma unroll
  for (int i = 0; i < 4; ++i) {
    const int row = i * 32 + r;
    const int gs = s ^ (row & 7);
    gload_lds16(g + ((row0 + row) << 10) + k0 + (gs << 3), lds + row * 64 + s * 8);
  }
}

__device__ __forceinline__ void stage64x64(const unsigned short* __restrict__ g,
                                           size_t row0, int k0,
                                           unsigned short* lds, int tid) {
  const int r = tid >> 3, s = tid & 7;
  #pragma unroll
  for (int i = 0; i < 2; ++i) {
    const int row = i * 32 + r;
    const int gs = s ^ (row & 7);
    gload_lds16(g + ((row0 + row) << 10) + k0 + (gs << 3), lds + row * 64 + s * 8);
  }
}

// ---------------- fused delta + B/C projection GEMM (k_out structure) ----------------
// by<16 : delta[:, by*64 .. by*64+63] = softplus(xb . weff^T + b_dt), K=1024
// by==16: Bm,Cm = xb . WBC^T  (32 output cols)
__global__ __launch_bounds__(256, 2) void k_deltaBC(
    const unsigned short* __restrict__ xb, const unsigned short* __restrict__ weff,
    const unsigned short* __restrict__ WBC, const float* __restrict__ b_dt,
    float* __restrict__ delta, float* __restrict__ Bm, float* __restrict__ Cm) {
  __shared__ __align__(16) unsigned short As[2][128 * 64];  // 2x16KB
  __shared__ __align__(16) unsigned short Bs[2][64 * 64];   // 2x8KB
  const int tid = threadIdx.x;
  const int lane = tid & 63, wid = tid >> 6;
  const size_t row0 = (size_t)blockIdx.x * 128;
  const int by = blockIdx.y;
  const bool bc = (by == 16);
  f32x4 acc[2][4] = {};

  auto stageB = [&](int buf, int k0) {
    if (!bc) {
      stage64x64(weff, (size_t)by * 64, k0, Bs[buf], tid);
    } else {
      const int row = tid >> 3, s = tid & 7;       // 32 rows, 1 load/thread
      const int gs = s ^ (row & 7);
      gload_lds16(WBC + (size_t)row * D_ + k0 + (gs << 3), Bs[buf] + row * 64 + s * 8);
    }
  };

  stage128x64(xb, row0, 0, As[0], tid);
  stageB(0, 0);
  __syncthreads();

  int cur = 0;
  const int r = lane & 15, kg = lane >> 4;
  for (int t = 0; t < 16; ++t) {
    if (t + 1 < 16) {
      stage128x64(xb, row0, (t + 1) * 64, As[cur ^ 1], tid);
      stageB(cur ^ 1, (t + 1) * 64);
    }
    const int nlim = bc ? 2 : 4;
    #pragma unroll
    for (int ks = 0; ks < 2; ++ks) {
      bf16x8 a[2], b[4];
      #pragma unroll
      for (int m = 0; m < 2; ++m) {
        const int arow = wid * 32 + m * 16 + r;
        a[m] = *(const bf16x8*)&As[cur][arow * 64 + (((ks << 2) | kg) ^ (arow & 7)) * 8];
      }
      for (int n = 0; n < nlim; ++n) {
        const int brow = n * 16 + r;
        b[n] = *(const bf16x8*)&Bs[cur][brow * 64 + (((ks << 2) | kg) ^ (brow & 7)) * 8];
      }
      #pragma unroll
      for (int m = 0; m < 2; ++m)
        for (int n = 0; n < nlim; ++n)
          acc[m][n] = __builtin_amdgcn_mfma_f32_16x16x32_bf16(a[m], b[n], acc[m][n], 0, 0, 0);
    }
    __syncthreads();
    cur ^= 1;
  }

  const int cr = lane >> 4, cc = lane & 15;
  if (!bc) {
    #pragma unroll
    for (int m = 0; m < 2; ++m) {
      #pragma unroll
      for (int n = 0; n < 4; ++n) {
        const int d = by * 64 + n * 16 + cc;
        const float bd = b_dt[d];
        #pragma unroll
        for (int j = 0; j < 4; ++j) {
          size_t trow = row0 + wid * 32 + m * 16 + cr * 4 + j;
          float v = acc[m][n][j] + bd;
          float sp = fmaxf(v, 0.f) + log1pf(__expf(-fabsf(v)));
          delta[trow * D_ + d] = sp;
        }
      }
    }
  } else {
    #pragma unroll
    for (int m = 0; m < 2; ++m) {
      #pragma unroll
      for (int n = 0; n < 2; ++n) {
        const int col = n * 16 + cc;
        #pragma unroll
        for (int j = 0; j < 4; ++j) {
          size_t trow = row0 + wid * 32 + m * 16 + cr * 4 + j;
          float v = acc[m][n][j];
          if (col < 16) Bm[trow * N_ + col] = v;
          else          Cm[trow * N_ + col - 16] = v;
        }
      }
    }
  }
}

// ---------------- scan phase 1: per-chunk hend + delta-sum ----------------
__global__ __launch_bounds__(256) void k_scan1(
    const float* __restrict__ x, const float* __restrict__ delta,
    const float* __restrict__ Bm, const float* __restrict__ A_log,
    float* __restrict__ sdsum, float* __restrict__ hend) {
  __shared__ __align__(16) float sd[CL][64];
  __shared__ __align__(16) float sx[CL][64];
  __shared__ __align__(16) float sB[CL][N_];
  const int tid = threadIdx.x;
  const int db = blockIdx.x & 15;
  const int c  = (blockIdx.x >> 4) & (NC - 1);
  const int b  = blockIdx.x >> 10;
  const int d0 = db * 64;
  const size_t tokbase = (size_t)(b * S_ + c * CL);

  {
    int s = tid >> 4, jf = (tid & 15) * 4;
    size_t g = (tokbase + s) * D_ + d0 + jf;
    gload_lds16(&delta[g], &sd[s][jf]);
    gload_lds16(&x[g],     &sx[s][jf]);
    gload_lds16(&delta[g + (size_t)16 * D_], &sd[s + 16][jf]);
    gload_lds16(&x[g + (size_t)16 * D_],     &sx[s + 16][jf]);
    if (tid < 128) {
      int s2 = tid >> 2, nf = (tid & 3) * 4;
      gload_lds16(&Bm[(tokbase + s2) * N_ + nf], &sB[s2][nf]);
    }
  }
  const int nq = tid & 3, dl = tid >> 2;
  const int d = d0 + dl;
  float4 av = *(const float4*)&A_log[(size_t)d * N_ + nq * 4];
  float Ad0 = -__expf(av.x), Ad1 = -__expf(av.y);
  float Ad2 = -__expf(av.z), Ad3 = -__expf(av.w);
  __syncthreads();

  float sds = 0.f;
  float h0 = 0.f, h1 = 0.f, h2 = 0.f, h3 = 0.f;
  #pragma unroll 8
  for (int s = 0; s < CL; ++s) {
    float dlt = sd[s][dl];
    float dbx = dlt * sx[s][dl];
    sds += dlt;
    float4 Bv = *(const float4*)&sB[s][nq * 4];
    float da0 = __expf(dlt * Ad0), da1 = __expf(dlt * Ad1);
    float da2 = __expf(dlt * Ad2), da3 = __expf(dlt * Ad3);
    h0 = da0 * h0 + dbx * Bv.x;
    h1 = da1 * h1 + dbx * Bv.y;
    h2 = da2 * h2 + dbx * Bv.z;
    h3 = da3 * h3 + dbx * Bv.w;
  }
  size_t o = (((size_t)(b * NC + c)) * D_ + d) * N_ + nq * 4;
  *(float4*)&hend[o] = make_float4(h0, h1, h2, h3);
  if (nq == 0) sdsum[(size_t)(b * NC + c) * D_ + d] = sds;
}

// ---------------- scan phase 2: scan chunk summaries ----------------
__global__ __launch_bounds__(256) void k_scan2(
    const float* __restrict__ sdsum, const float* __restrict__ hend,
    const float* __restrict__ A_log, float* __restrict__ hstart) {
  int g = blockIdx.x * 256 + threadIdx.x;   // B_*D_*N_ = 32768 threads
  int n = g & (N_ - 1);
  int d = (g >> 4) & (D_ - 1);
  int b = g >> 14;
  float Ad = -__expf(A_log[(size_t)d * N_ + n]);
  float h = 0.f;
  for (int c = 0; c < NC; ++c) {
    size_t idx = (((size_t)b * NC + c) * D_ + d) * N_ + n;
    float ap = __expf(Ad * sdsum[(size_t)(b * NC + c) * D_ + d]);
    hstart[idx] = h;
    h = ap * h + hend[idx];
  }
}

// ---------------- scan phase 3: recompute + y + fused residual ----------------
__global__ __launch_bounds__(256) void k_scan3(
    const float* __restrict__ x, const float* __restrict__ delta,
    const float* __restrict__ Bm, const float* __restrict__ Cm,
    const float* __restrict__ A_log, const float* __restrict__ hstart,
    const float* __restrict__ Dp, float* __restrict__ ypre) {
  __shared__ __align__(16) float sd[CL][64];
  __shared__ __align__(16) float sx[CL][64];
  __shared__ __align__(16) float sB[CL][N_];
  __shared__ __align__(16) float sC[CL][N_];
  __shared__ __align__(16) float sy[CL][64];
  const int tid = threadIdx.x;
  const int db = blockIdx.x & 15;
  const int c  = (blockIdx.x >> 4) & (NC - 1);
  const int b  = blockIdx.x >> 10;
  const int d0 = db * 64;
  const size_t tokbase = (size_t)(b * S_ + c * CL);

  {
    int s = tid >> 4, jf = (tid & 15) * 4;
    size_t g = (tokbase + s) * D_ + d0 + jf;
    gload_lds16(&delta[g], &sd[s][jf]);
    gload_lds16(&x[g],     &sx[s][jf]);
    gload_lds16(&delta[g + (size_t)16 * D_], &sd[s + 16][jf]);
    gload_lds16(&x[g + (size_t)16 * D_],     &sx[s + 16][jf]);
    if (tid < 128) {
      int s2 = tid >> 2, nf = (tid & 3) * 4;
      gload_lds16(&Bm[(tokbase + s2) * N_ + nf], &sB[s2][nf]);
      gload_lds16(&Cm[(tokbase + s2) * N_ + nf], &sC[s2][nf]);
    }
  }
  const int nq = tid & 3, dl = tid >> 2;
  const int d = d0 + dl;
  float4 av = *(const float4*)&A_log[(size_t)d * N_ + nq * 4];
  float Ad0 = -__expf(av.x), Ad1 = -__expf(av.y);
  float Ad2 = -__expf(av.z), Ad3 = -__expf(av.w);
  float h0, h1, h2, h3;
  {
    size_t o = (((size_t)(b * NC + c)) * D_ + d) * N_ + nq * 4;
    float4 v = *(const float4*)&hstart[o];
    h0 = v.x; h1 = v.y; h2 = v.z; h3 = v.w;
  }
  const float Dpd = Dp[d];
  __syncthreads();

  #pragma unroll 8
  for (int s = 0; s < CL; ++s) {
    float dlt = sd[s][dl];
    float xv  = sx[s][dl];
    float dbx = dlt * xv;
    float4 Bv = *(const float4*)&sB[s][nq * 4];
    float4 Cv = *(const float4*)&sC[s][nq * 4];
    float da0 = __expf(dlt * Ad0), da1 = __expf(dlt * Ad1);
    float da2 = __expf(dlt * Ad2), da3 = __expf(dlt * Ad3);
    h0 = da0 * h0 + dbx * Bv.x;
    h1 = da1 * h1 + dbx * Bv.y;
    h2 = da2 * h2 + dbx * Bv.z;
    h3 = da3 * h3 + dbx * Bv.w;
    float y = h0 * Cv.x + h1 * Cv.y + h2 * Cv.z + h3 * Cv.w;
    y += __shfl_xor(y, 1);
    y += __shfl_xor(y, 2);
    if (nq == 0) sy[s][dl] = y + Dpd * xv;
  }
  __syncthreads();
  {
    int s = tid >> 3, j = (tid & 7) * 8;
    size_t g = (tokbase + s) * D_ + d0 + j;
    *(float4*)&ypre[g]     = *(float4*)&sy[s][j];
    *(float4*)&ypre[g + 4] = *(float4*)&sy[s][j + 4];
  }
}

// ---------------- layernorm (residual already fused) -> bf16 y ----------------
__device__ __forceinline__ float block_sum256(float v, float* sm) {
  #pragma unroll
  for (int o = 32; o > 0; o >>= 1) v += __shfl_down(v, o, 64);
  int w = threadIdx.x >> 6;
  __syncthreads();
  if ((threadIdx.x & 63) == 0) sm[w] = v;
  __syncthreads();
  return (sm[0] + sm[1]) + (sm[2] + sm[3]);
}

__global__ __launch_bounds__(256) void k_ln(
    const float* __restrict__ ypre, const float* __restrict__ g,
    const float* __restrict__ bta, unsigned short* __restrict__ ybf) {
  __shared__ float sm[4];
  const int t = blockIdx.x;
  const int tid = threadIdx.x;
  size_t base = (size_t)t * D_ + tid * 4;
  float4 v = *(const float4*)&ypre[base];
  float s1 = block_sum256(v.x + v.y + v.z + v.w, sm);
  float mu = s1 * (1.f / D_);
  float cx = v.x - mu, cy = v.y - mu, cz = v.z - mu, cw = v.w - mu;
  float s2 = block_sum256(cx*cx + cy*cy + cz*cz + cw*cw, sm);
  float rs = rsqrtf(s2 * (1.f / D_) + 1e-5f);
  float4 gg = *(const float4*)&g[tid * 4];
  float4 bb = *(const float4*)&bta[tid * 4];
  ushort4 o;
  o.x = f2b(cx * rs * gg.x + bb.x);
  o.y = f2b(cy * rs * gg.y + bb.y);
  o.z = f2b(cz * rs * gg.z + bb.z);
  o.w = f2b(cw * rs * gg.w + bb.w);
  *(ushort4*)&ybf[base] = o;
}

// ---------------- output GEMM: O = Y[4096,1024] x W_out^T, bf16 MFMA ----------------
__global__ __launch_bounds__(256, 2) void k_out(const unsigned short* __restrict__ Y,
                                                const unsigned short* __restrict__ W,
                                                float* __restrict__ O) {
  __shared__ __align__(16) unsigned short As[2][128 * 64];
  __shared__ __align__(16) unsigned short Bs[2][64 * 64];
  const int tid = threadIdx.x;
  const int lane = tid & 63, wid = tid >> 6;
  const size_t row0 = (size_t)blockIdx.x * 128;
  const size_t col0 = (size_t)blockIdx.y * 64;
  f32x4 acc[2][4] = {};

  stage128x64(Y, row0, 0, As[0], tid);
  stage64x64(W, col0, 0, Bs[0], tid);
  __syncthreads();

  int cur = 0;
  const int r = lane & 15, kg = lane >> 4;
  for (int t = 0; t < 16; ++t) {
    if (t + 1 < 16) {
      stage128x64(Y, row0, (t + 1) * 64, As[cur ^ 1], tid);
      stage64x64(W, col0, (t + 1) * 64, Bs[cur ^ 1], tid);
    }
    #pragma unroll
    for (int ks = 0; ks < 2; ++ks) {
      bf16x8 a[2], b[4];
      #pragma unroll
      for (int m = 0; m < 2; ++m) {
        const int arow = wid * 32 + m * 16 + r;
        a[m] = *(const bf16x8*)&As[cur][arow * 64 + (((ks << 2) | kg) ^ (arow & 7)) * 8];
      }
      #pragma unroll
      for (int n = 0; n < 4; ++n) {
        const int brow = n * 16 + r;
        b[n] = *(const bf16x8*)&Bs[cur][brow * 64 + (((ks << 2) | kg) ^ (brow & 7)) * 8];
      }
      #pragma unroll
      for (int m = 0; m < 2; ++m)
        #pragma unroll
        for (int n = 0; n < 4; ++n)
          acc[m][n] = __builtin_amdgcn_mfma_f32_16x16x32_bf16(a[m], b[n], acc[m][n], 0, 0, 0);
    }
    __syncthreads();
    cur ^= 1;
  }

  const int cr = lane >> 4, cc = lane & 15;
  #pragma unroll
  for (int m = 0; m < 2; ++m) {
    #pragma unroll
    for (int n = 0; n < 4; ++n) {
      size_t orow = row0 + wid * 32 + m * 16 + cr * 4;
      float* op = O + orow * D_ + col0 + n * 16 + cc;
      #pragma unroll
      for (int j = 0; j < 4; ++j) op[(size_t)j * D_] = acc[m][n][j];
    }
  }
}

extern "C" void kernel_launch(void* const* d_in, const int* in_sizes, int n_in,
                              void* d_out, int out_size, void* d_ws, size_t ws_size,
                              hipStream_t stream) {
  const float* x     = (const float*)d_in[0];
  const float* W_dtw = (const float*)d_in[1];
  const float* W_dt  = (const float*)d_in[2];
  const float* b_dt  = (const float*)d_in[3];
  const float* A_log = (const float*)d_in[4];
  const float* W_B   = (const float*)d_in[5];
  const float* W_C   = (const float*)d_in[6];
  const float* Dp    = (const float*)d_in[7];
  const float* ln_g  = (const float*)d_in[8];
  const float* ln_b  = (const float*)d_in[9];
  const float* W_out = (const float*)d_in[10];
  float* out = (float*)d_out;

  // ws_size = 256 MiB; ~72 MB used, all buffers dedicated.
  float* ws = (float*)d_ws;
  float* delta  = ws;                                   // 4,194,304 f
  float* ypre   = delta  + (size_t)BS_ * D_;            // 4,194,304 f
  float* Bm     = ypre   + (size_t)BS_ * D_;            //    65,536 f
  float* Cm     = Bm     + (size_t)BS_ * N_;            //    65,536 f
  float* hend   = Cm     + (size_t)BS_ * N_;            // 2,097,152 f
  float* hstart = hend   + (size_t)B_ * NC * D_ * N_;   // 2,097,152 f
  float* sdsum  = hstart + (size_t)B_ * NC * D_ * N_;   //   131,072 f
  unsigned short* xb    = (unsigned short*)(sdsum + (size_t)B_ * NC * D_);
  unsigned short* WBC   = xb    + (size_t)BS_ * D_;     // 32,768 u16
  unsigned short* wdtb  = WBC   + (size_t)32 * D_;      // 65,536 u16
  unsigned short* wdtwT = wdtb  + (size_t)D_ * R_;      // 65,536 u16
  unsigned short* weff  = wdtwT + (size_t)D_ * R_;      // 1,048,576 u16
  unsigned short* wob   = weff  + (size_t)D_ * D_;      // 1,048,576 u16
  unsigned short* ybf   = wob   + (size_t)D_ * D_;      // 4,194,304 u16

  k_castall<<<dim3(5280), dim3(256), 0, stream>>>(x, W_B, W_C, W_dt, W_out, W_dtw,
                                                  xb, WBC, wdtb, wob, wdtwT);
  k_weff<<<dim3(8, 8), dim3(256), 0, stream>>>(wdtb, wdtwT, weff);
  k_deltaBC<<<dim3(BS_ / 128, 17), dim3(256), 0, stream>>>(xb, weff, WBC, b_dt,
                                                           delta, Bm, Cm);
  k_scan1<<<dim3(B_ * NC * (D_ / 64)), dim3(256), 0, stream>>>(x, delta, Bm, A_log,
                                                               sdsum, hend);
  k_scan2<<<dim3(B_ * D_ * N_ / 256), dim3(256), 0, stream>>>(sdsum, hend, A_log, hstart);
  k_scan3<<<dim3(B_ * NC * (D_ / 64)), dim3(256), 0, stream>>>(x, delta, Bm, Cm,
                                                               A_log, hstart, Dp, ypre);
  k_ln<<<dim3(BS_), dim3(256), 0, stream>>>(ypre, ln_g, ln_b, ybf);
  k_out<<<dim3(BS_ / 128, D_ / 64), dim3(256), 0, stream>>>(ybf, wob, out);
}

// Round 8
// 113.785 us; speedup vs baseline: 16.3521x; 16.3521x over previous
//
#include <hip/hip_runtime.h>
#include <hip/hip_bf16.h>

#define B_ 2
#define S_ 2048
#define D_ 1024
#define N_ 16
#define R_ 64
#define NC 64          // number of scan chunks
#define CL 32          // chunk length  (NC*CL == S_)
#define BS_ (B_*S_)

typedef __attribute__((ext_vector_type(4))) float f32x4;
typedef __attribute__((ext_vector_type(8))) short bf16x8;
typedef __attribute__((ext_vector_type(8))) unsigned short u16x8;

__device__ __forceinline__ unsigned short f2b(float v) {
  unsigned u = __builtin_bit_cast(unsigned, v);
  unsigned r = ((u >> 16) & 1u) + 0x7FFFu;
  return (unsigned short)((u + r) >> 16);
}

__device__ __forceinline__ void gload_lds16(const void* g, void* l) {
  __builtin_amdgcn_global_load_lds(
      (const __attribute__((address_space(1))) unsigned int*)g,
      (__attribute__((address_space(3))) unsigned int*)l, 16, 0, 0);
}

// ---------------- fp32 -> bf16 casts (x + all weights) ----------------
// regions (fp32 element offsets, all multiples of 1024):
//  [0,       4194304) x     -> xb
//  [4194304, 4210688) W_B   -> WBC rows 0..15
//  [4210688, 4227072) W_C   -> WBC rows 16..31
//  [4227072, 4292608) W_dt  -> wdtb  [1024][64]
//  [4292608, 5341184) W_out -> wob   [1024][1024]
//  [5341184, 5406720) W_dtw -> TRANSPOSED to wdtwT [e][r]
__global__ __launch_bounds__(256) void k_castall(
    const float* __restrict__ x, const float* __restrict__ W_B,
    const float* __restrict__ W_C, const float* __restrict__ W_dt,
    const float* __restrict__ W_out, const float* __restrict__ W_dtw,
    unsigned short* __restrict__ xb, unsigned short* __restrict__ WBC,
    unsigned short* __restrict__ wdtb, unsigned short* __restrict__ wob,
    unsigned short* __restrict__ wdtwT) {
  int i = (blockIdx.x * 256 + threadIdx.x) * 4;   // grid covers 5406720 elems
  if (i < 5341184) {
    const float* s; unsigned short* d; int off;
    if (i < 4194304)      { s = x;     d = xb;          off = 0; }
    else if (i < 4210688) { s = W_B;   d = WBC;         off = 4194304; }
    else if (i < 4227072) { s = W_C;   d = WBC + 16384; off = 4210688; }
    else if (i < 4292608) { s = W_dt;  d = wdtb;        off = 4227072; }
    else                  { s = W_out; d = wob;         off = 4292608; }
    int j = i - off;
    float4 v = *(const float4*)&s[j];
    ushort4 o;
    o.x = f2b(v.x); o.y = f2b(v.y); o.z = f2b(v.z); o.w = f2b(v.w);
    *(ushort4*)&d[j] = o;
  } else {
    int j = i - 5341184;            // flat index into W_dtw [64][1024]
    int r = j >> 10, e = j & 1023;
    float4 v = *(const float4*)&W_dtw[j];
    wdtwT[(size_t)(e + 0) * 64 + r] = f2b(v.x);
    wdtwT[(size_t)(e + 1) * 64 + r] = f2b(v.y);
    wdtwT[(size_t)(e + 2) * 64 + r] = f2b(v.z);
    wdtwT[(size_t)(e + 3) * 64 + r] = f2b(v.w);
  }
}

// ---------------- W_eff = W_dt[1024,64] x W_dtw[64,1024] -> bf16 [d][e] ----------------
__global__ __launch_bounds__(256) void k_weff(
    const unsigned short* __restrict__ wdtb, const unsigned short* __restrict__ wdtwT,
    unsigned short* __restrict__ weff) {
  __shared__ __align__(16) unsigned short As[128 * 64];
  __shared__ __align__(16) unsigned short Bs[128 * 64];
  const int tid = threadIdx.x;
  const int lane = tid & 63, wid = tid >> 6;
  const int wr = wid >> 1, wc = wid & 1;
  const size_t row0 = (size_t)blockIdx.x * 128;   // d
  const size_t col0 = (size_t)blockIdx.y * 128;   // e
  f32x4 acc[4][4] = {};
  {
    const int r = tid >> 3, s = tid & 7;
    #pragma unroll
    for (int i = 0; i < 4; ++i) {
      const int row = i * 32 + r;
      const int gs = s ^ (row & 7);
      gload_lds16(wdtb + (row0 + row) * R_ + gs * 8, As + row * 64 + s * 8);
      gload_lds16(wdtwT + (col0 + row) * R_ + gs * 8, Bs + row * 64 + s * 8);
    }
  }
  __syncthreads();
  const int r = lane & 15, kg = lane >> 4;
  #pragma unroll
  for (int ks = 0; ks < 2; ++ks) {
    bf16x8 a[4], b[4];
    #pragma unroll
    for (int m = 0; m < 4; ++m) {
      const int arow = wr * 64 + m * 16 + r;
      a[m] = *(const bf16x8*)&As[arow * 64 + (((ks << 2) | kg) ^ (arow & 7)) * 8];
    }
    #pragma unroll
    for (int n = 0; n < 4; ++n) {
      const int brow = wc * 64 + n * 16 + r;
      b[n] = *(const bf16x8*)&Bs[brow * 64 + (((ks << 2) | kg) ^ (brow & 7)) * 8];
    }
    #pragma unroll
    for (int m = 0; m < 4; ++m)
      #pragma unroll
      for (int n = 0; n < 4; ++n)
        acc[m][n] = __builtin_amdgcn_mfma_f32_16x16x32_bf16(a[m], b[n], acc[m][n], 0, 0, 0);
  }
  const int cr = lane >> 4, cc = lane & 15;
  #pragma unroll
  for (int m = 0; m < 4; ++m)
    #pragma unroll
    for (int n = 0; n < 4; ++n)
      #pragma unroll
      for (int j = 0; j < 4; ++j)
        weff[(row0 + wr * 64 + m * 16 + cr * 4 + j) * D_ + col0 + wc * 64 + n * 16 + cc]
            = f2b(acc[m][n][j]);
}

// ---------------- shared staging helpers (k_out structure) ----------------
__device__ __forceinline__ void stage128x64(const unsigned short* __restrict__ g,
                                            size_t row0, int k0,
                                            unsigned short* lds, int tid) {
  const int r = tid >> 3, s = tid & 7;
  #pragma unroll
  for (int i = 0; i < 4; ++i) {
    const int row = i * 32 + r;
    const int gs = s ^ (row & 7);
    gload_lds16(g + ((row0 + row) << 10) + k0 + (gs << 3), lds + row * 64 + s * 8);
  }
}

__device__ __forceinline__ void stage64x64(const unsigned short* __restrict__ g,
                                           size_t row0, int k0,
                                           unsigned short* lds, int tid) {
  const int r = tid >> 3, s = tid & 7;
  #pragma unroll
  for (int i = 0; i < 2; ++i) {
    const int row = i * 32 + r;
    const int gs = s ^ (row & 7);
    gload_lds16(g + ((row0 + row) << 10) + k0 + (gs << 3), lds + row * 64 + s * 8);
  }
}

// ---------------- fused delta + B/C projection GEMM (k_out structure) ----------------
// by<16 : delta[:, by*64 .. by*64+63] = softplus(xb . weff^T + b_dt), K=1024
// by==16: Bm,Cm = xb . WBC^T  (32 output cols)
// NOTE: both MFMA branches are fully unrolled with compile-time indices --
// a runtime loop bound here sends acc[][] to scratch (rule #20, R7 regression).
__global__ __launch_bounds__(256, 2) void k_deltaBC(
    const unsigned short* __restrict__ xb, const unsigned short* __restrict__ weff,
    const unsigned short* __restrict__ WBC, const float* __restrict__ b_dt,
    float* __restrict__ delta, float* __restrict__ Bm, float* __restrict__ Cm) {
  __shared__ __align__(16) unsigned short As[2][128 * 64];  // 2x16KB
  __shared__ __align__(16) unsigned short Bs[2][64 * 64];   // 2x8KB
  const int tid = threadIdx.x;
  const int lane = tid & 63, wid = tid >> 6;
  const size_t row0 = (size_t)blockIdx.x * 128;
  const int by = blockIdx.y;
  const bool bc = (by == 16);
  f32x4 acc[2][4] = {};

  auto stageB = [&](int buf, int k0) {
    if (!bc) {
      stage64x64(weff, (size_t)by * 64, k0, Bs[buf], tid);
    } else {
      const int row = tid >> 3, s = tid & 7;       // 32 rows, 1 load/thread
      const int gs = s ^ (row & 7);
      gload_lds16(WBC + (size_t)row * D_ + k0 + (gs << 3), Bs[buf] + row * 64 + s * 8);
    }
  };

  stage128x64(xb, row0, 0, As[0], tid);
  stageB(0, 0);
  __syncthreads();

  int cur = 0;
  const int r = lane & 15, kg = lane >> 4;
  for (int t = 0; t < 16; ++t) {
    if (t + 1 < 16) {
      stage128x64(xb, row0, (t + 1) * 64, As[cur ^ 1], tid);
      stageB(cur ^ 1, (t + 1) * 64);
    }
    if (!bc) {
      #pragma unroll
      for (int ks = 0; ks < 2; ++ks) {
        bf16x8 a[2], b[4];
        #pragma unroll
        for (int m = 0; m < 2; ++m) {
          const int arow = wid * 32 + m * 16 + r;
          a[m] = *(const bf16x8*)&As[cur][arow * 64 + (((ks << 2) | kg) ^ (arow & 7)) * 8];
        }
        #pragma unroll
        for (int n = 0; n < 4; ++n) {
          const int brow = n * 16 + r;
          b[n] = *(const bf16x8*)&Bs[cur][brow * 64 + (((ks << 2) | kg) ^ (brow & 7)) * 8];
        }
        #pragma unroll
        for (int m = 0; m < 2; ++m)
          #pragma unroll
          for (int n = 0; n < 4; ++n)
            acc[m][n] = __builtin_amdgcn_mfma_f32_16x16x32_bf16(a[m], b[n], acc[m][n], 0, 0, 0);
      }
    } else {
      #pragma unroll
      for (int ks = 0; ks < 2; ++ks) {
        bf16x8 a[2], b[2];
        #pragma unroll
        for (int m = 0; m < 2; ++m) {
          const int arow = wid * 32 + m * 16 + r;
          a[m] = *(const bf16x8*)&As[cur][arow * 64 + (((ks << 2) | kg) ^ (arow & 7)) * 8];
        }
        #pragma unroll
        for (int n = 0; n < 2; ++n) {
          const int brow = n * 16 + r;
          b[n] = *(const bf16x8*)&Bs[cur][brow * 64 + (((ks << 2) | kg) ^ (brow & 7)) * 8];
        }
        #pragma unroll
        for (int m = 0; m < 2; ++m)
          #pragma unroll
          for (int n = 0; n < 2; ++n)
            acc[m][n] = __builtin_amdgcn_mfma_f32_16x16x32_bf16(a[m], b[n], acc[m][n], 0, 0, 0);
      }
    }
    __syncthreads();
    cur ^= 1;
  }

  const int cr = lane >> 4, cc = lane & 15;
  if (!bc) {
    #pragma unroll
    for (int m = 0; m < 2; ++m) {
      #pragma unroll
      for (int n = 0; n < 4; ++n) {
        const int d = by * 64 + n * 16 + cc;
        const float bd = b_dt[d];
        #pragma unroll
        for (int j = 0; j < 4; ++j) {
          size_t trow = row0 + wid * 32 + m * 16 + cr * 4 + j;
          float v = acc[m][n][j] + bd;
          float sp = fmaxf(v, 0.f) + log1pf(__expf(-fabsf(v)));
          delta[trow * D_ + d] = sp;
        }
      }
    }
  } else {
    #pragma unroll
    for (int m = 0; m < 2; ++m) {
      #pragma unroll
      for (int n = 0; n < 2; ++n) {
        const int col = n * 16 + cc;
        #pragma unroll
        for (int j = 0; j < 4; ++j) {
          size_t trow = row0 + wid * 32 + m * 16 + cr * 4 + j;
          float v = acc[m][n][j];
          if (col < 16) Bm[trow * N_ + col] = v;
          else          Cm[trow * N_ + col - 16] = v;
        }
      }
    }
  }
}

// ---------------- scan phase 1: per-chunk hend + delta-sum ----------------
__global__ __launch_bounds__(256) void k_scan1(
    const float* __restrict__ x, const float* __restrict__ delta,
    const float* __restrict__ Bm, const float* __restrict__ A_log,
    float* __restrict__ sdsum, float* __restrict__ hend) {
  __shared__ __align__(16) float sd[CL][64];
  __shared__ __align__(16) float sx[CL][64];
  __shared__ __align__(16) float sB[CL][N_];
  const int tid = threadIdx.x;
  const int db = blockIdx.x & 15;
  const int c  = (blockIdx.x >> 4) & (NC - 1);
  const int b  = blockIdx.x >> 10;
  const int d0 = db * 64;
  const size_t tokbase = (size_t)(b * S_ + c * CL);

  {
    int s = tid >> 4, jf = (tid & 15) * 4;
    size_t g = (tokbase + s) * D_ + d0 + jf;
    gload_lds16(&delta[g], &sd[s][jf]);
    gload_lds16(&x[g],     &sx[s][jf]);
    gload_lds16(&delta[g + (size_t)16 * D_], &sd[s + 16][jf]);
    gload_lds16(&x[g + (size_t)16 * D_],     &sx[s + 16][jf]);
    if (tid < 128) {
      int s2 = tid >> 2, nf = (tid & 3) * 4;
      gload_lds16(&Bm[(tokbase + s2) * N_ + nf], &sB[s2][nf]);
    }
  }
  const int nq = tid & 3, dl = tid >> 2;
  const int d = d0 + dl;
  float4 av = *(const float4*)&A_log[(size_t)d * N_ + nq * 4];
  float Ad0 = -__expf(av.x), Ad1 = -__expf(av.y);
  float Ad2 = -__expf(av.z), Ad3 = -__expf(av.w);
  __syncthreads();

  float sds = 0.f;
  float h0 = 0.f, h1 = 0.f, h2 = 0.f, h3 = 0.f;
  #pragma unroll 8
  for (int s = 0; s < CL; ++s) {
    float dlt = sd[s][dl];
    float dbx = dlt * sx[s][dl];
    sds += dlt;
    float4 Bv = *(const float4*)&sB[s][nq * 4];
    float da0 = __expf(dlt * Ad0), da1 = __expf(dlt * Ad1);
    float da2 = __expf(dlt * Ad2), da3 = __expf(dlt * Ad3);
    h0 = da0 * h0 + dbx * Bv.x;
    h1 = da1 * h1 + dbx * Bv.y;
    h2 = da2 * h2 + dbx * Bv.z;
    h3 = da3 * h3 + dbx * Bv.w;
  }
  size_t o = (((size_t)(b * NC + c)) * D_ + d) * N_ + nq * 4;
  *(float4*)&hend[o] = make_float4(h0, h1, h2, h3);
  if (nq == 0) sdsum[(size_t)(b * NC + c) * D_ + d] = sds;
}

// ---------------- scan phase 2: scan chunk summaries ----------------
__global__ __launch_bounds__(256) void k_scan2(
    const float* __restrict__ sdsum, const float* __restrict__ hend,
    const float* __restrict__ A_log, float* __restrict__ hstart) {
  int g = blockIdx.x * 256 + threadIdx.x;   // B_*D_*N_ = 32768 threads
  int n = g & (N_ - 1);
  int d = (g >> 4) & (D_ - 1);
  int b = g >> 14;
  float Ad = -__expf(A_log[(size_t)d * N_ + n]);
  float h = 0.f;
  for (int c = 0; c < NC; ++c) {
    size_t idx = (((size_t)b * NC + c) * D_ + d) * N_ + n;
    float ap = __expf(Ad * sdsum[(size_t)(b * NC + c) * D_ + d]);
    hstart[idx] = h;
    h = ap * h + hend[idx];
  }
}

// ---------------- scan phase 3: recompute + y + fused residual ----------------
__global__ __launch_bounds__(256) void k_scan3(
    const float* __restrict__ x, const float* __restrict__ delta,
    const float* __restrict__ Bm, const float* __restrict__ Cm,
    const float* __restrict__ A_log, const float* __restrict__ hstart,
    const float* __restrict__ Dp, float* __restrict__ ypre) {
  __shared__ __align__(16) float sd[CL][64];
  __shared__ __align__(16) float sx[CL][64];
  __shared__ __align__(16) float sB[CL][N_];
  __shared__ __align__(16) float sC[CL][N_];
  __shared__ __align__(16) float sy[CL][64];
  const int tid = threadIdx.x;
  const int db = blockIdx.x & 15;
  const int c  = (blockIdx.x >> 4) & (NC - 1);
  const int b  = blockIdx.x >> 10;
  const int d0 = db * 64;
  const size_t tokbase = (size_t)(b * S_ + c * CL);

  {
    int s = tid >> 4, jf = (tid & 15) * 4;
    size_t g = (tokbase + s) * D_ + d0 + jf;
    gload_lds16(&delta[g], &sd[s][jf]);
    gload_lds16(&x[g],     &sx[s][jf]);
    gload_lds16(&delta[g + (size_t)16 * D_], &sd[s + 16][jf]);
    gload_lds16(&x[g + (size_t)16 * D_],     &sx[s + 16][jf]);
    if (tid < 128) {
      int s2 = tid >> 2, nf = (tid & 3) * 4;
      gload_lds16(&Bm[(tokbase + s2) * N_ + nf], &sB[s2][nf]);
      gload_lds16(&Cm[(tokbase + s2) * N_ + nf], &sC[s2][nf]);
    }
  }
  const int nq = tid & 3, dl = tid >> 2;
  const int d = d0 + dl;
  float4 av = *(const float4*)&A_log[(size_t)d * N_ + nq * 4];
  float Ad0 = -__expf(av.x), Ad1 = -__expf(av.y);
  float Ad2 = -__expf(av.z), Ad3 = -__expf(av.w);
  float h0, h1, h2, h3;
  {
    size_t o = (((size_t)(b * NC + c)) * D_ + d) * N_ + nq * 4;
    float4 v = *(const float4*)&hstart[o];
    h0 = v.x; h1 = v.y; h2 = v.z; h3 = v.w;
  }
  const float Dpd = Dp[d];
  __syncthreads();

  #pragma unroll 8
  for (int s = 0; s < CL; ++s) {
    float dlt = sd[s][dl];
    float xv  = sx[s][dl];
    float dbx = dlt * xv;
    float4 Bv = *(const float4*)&sB[s][nq * 4];
    float4 Cv = *(const float4*)&sC[s][nq * 4];
    float da0 = __expf(dlt * Ad0), da1 = __expf(dlt * Ad1);
    float da2 = __expf(dlt * Ad2), da3 = __expf(dlt * Ad3);
    h0 = da0 * h0 + dbx * Bv.x;
    h1 = da1 * h1 + dbx * Bv.y;
    h2 = da2 * h2 + dbx * Bv.z;
    h3 = da3 * h3 + dbx * Bv.w;
    float y = h0 * Cv.x + h1 * Cv.y + h2 * Cv.z + h3 * Cv.w;
    y += __shfl_xor(y, 1);
    y += __shfl_xor(y, 2);
    if (nq == 0) sy[s][dl] = y + Dpd * xv;
  }
  __syncthreads();
  {
    int s = tid >> 3, j = (tid & 7) * 8;
    size_t g = (tokbase + s) * D_ + d0 + j;
    *(float4*)&ypre[g]     = *(float4*)&sy[s][j];
    *(float4*)&ypre[g + 4] = *(float4*)&sy[s][j + 4];
  }
}

// ---------------- layernorm (residual already fused) -> bf16 y ----------------
__device__ __forceinline__ float block_sum256(float v, float* sm) {
  #pragma unroll
  for (int o = 32; o > 0; o >>= 1) v += __shfl_down(v, o, 64);
  int w = threadIdx.x >> 6;
  __syncthreads();
  if ((threadIdx.x & 63) == 0) sm[w] = v;
  __syncthreads();
  return (sm[0] + sm[1]) + (sm[2] + sm[3]);
}

__global__ __launch_bounds__(256) void k_ln(
    const float* __restrict__ ypre, const float* __restrict__ g,
    const float* __restrict__ bta, unsigned short* __restrict__ ybf) {
  __shared__ float sm[4];
  const int t = blockIdx.x;
  const int tid = threadIdx.x;
  size_t base = (size_t)t * D_ + tid * 4;
  float4 v = *(const float4*)&ypre[base];
  float s1 = block_sum256(v.x + v.y + v.z + v.w, sm);
  float mu = s1 * (1.f / D_);
  float cx = v.x - mu, cy = v.y - mu, cz = v.z - mu, cw = v.w - mu;
  float s2 = block_sum256(cx*cx + cy*cy + cz*cz + cw*cw, sm);
  float rs = rsqrtf(s2 * (1.f / D_) + 1e-5f);
  float4 gg = *(const float4*)&g[tid * 4];
  float4 bb = *(const float4*)&bta[tid * 4];
  ushort4 o;
  o.x = f2b(cx * rs * gg.x + bb.x);
  o.y = f2b(cy * rs * gg.y + bb.y);
  o.z = f2b(cz * rs * gg.z + bb.z);
  o.w = f2b(cw * rs * gg.w + bb.w);
  *(ushort4*)&ybf[base] = o;
}

// ---------------- output GEMM: O = Y[4096,1024] x W_out^T, bf16 MFMA ----------------
__global__ __launch_bounds__(256, 2) void k_out(const unsigned short* __restrict__ Y,
                                                const unsigned short* __restrict__ W,
                                                float* __restrict__ O) {
  __shared__ __align__(16) unsigned short As[2][128 * 64];
  __shared__ __align__(16) unsigned short Bs[2][64 * 64];
  const int tid = threadIdx.x;
  const int lane = tid & 63, wid = tid >> 6;
  const size_t row0 = (size_t)blockIdx.x * 128;
  const size_t col0 = (size_t)blockIdx.y * 64;
  f32x4 acc[2][4] = {};

  stage128x64(Y, row0, 0, As[0], tid);
  stage64x64(W, col0, 0, Bs[0], tid);
  __syncthreads();

  int cur = 0;
  const int r = lane & 15, kg = lane >> 4;
  for (int t = 0; t < 16; ++t) {
    if (t + 1 < 16) {
      stage128x64(Y, row0, (t + 1) * 64, As[cur ^ 1], tid);
      stage64x64(W, col0, (t + 1) * 64, Bs[cur ^ 1], tid);
    }
    #pragma unroll
    for (int ks = 0; ks < 2; ++ks) {
      bf16x8 a[2], b[4];
      #pragma unroll
      for (int m = 0; m < 2; ++m) {
        const int arow = wid * 32 + m * 16 + r;
        a[m] = *(const bf16x8*)&As[cur][arow * 64 + (((ks << 2) | kg) ^ (arow & 7)) * 8];
      }
      #pragma unroll
      for (int n = 0; n < 4; ++n) {
        const int brow = n * 16 + r;
        b[n] = *(const bf16x8*)&Bs[cur][brow * 64 + (((ks << 2) | kg) ^ (brow & 7)) * 8];
      }
      #pragma unroll
      for (int m = 0; m < 2; ++m)
        #pragma unroll
        for (int n = 0; n < 4; ++n)
          acc[m][n] = __builtin_amdgcn_mfma_f32_16x16x32_bf16(a[m], b[n], acc[m][n], 0, 0, 0);
    }
    __syncthreads();
    cur ^= 1;
  }

  const int cr = lane >> 4, cc = lane & 15;
  #pragma unroll
  for (int m = 0; m < 2; ++m) {
    #pragma unroll
    for (int n = 0; n < 4; ++n) {
      size_t orow = row0 + wid * 32 + m * 16 + cr * 4;
      float* op = O + orow * D_ + col0 + n * 16 + cc;
      #pragma unroll
      for (int j = 0; j < 4; ++j) op[(size_t)j * D_] = acc[m][n][j];
    }
  }
}

extern "C" void kernel_launch(void* const* d_in, const int* in_sizes, int n_in,
                              void* d_out, int out_size, void* d_ws, size_t ws_size,
                              hipStream_t stream) {
  const float* x     = (const float*)d_in[0];
  const float* W_dtw = (const float*)d_in[1];
  const float* W_dt  = (const float*)d_in[2];
  const float* b_dt  = (const float*)d_in[3];
  const float* A_log = (const float*)d_in[4];
  const float* W_B   = (const float*)d_in[5];
  const float* W_C   = (const float*)d_in[6];
  const float* Dp    = (const float*)d_in[7];
  const float* ln_g  = (const float*)d_in[8];
  const float* ln_b  = (const float*)d_in[9];
  const float* W_out = (const float*)d_in[10];
  float* out = (float*)d_out;

  // ws_size = 256 MiB; ~72 MB used, all buffers dedicated.
  float* ws = (float*)d_ws;
  float* delta  = ws;                                   // 4,194,304 f
  float* ypre   = delta  + (size_t)BS_ * D_;            // 4,194,304 f
  float* Bm     = ypre   + (size_t)BS_ * D_;            //    65,536 f
  float* Cm     = Bm     + (size_t)BS_ * N_;            //    65,536 f
  float* hend   = Cm     + (size_t)BS_ * N_;            // 2,097,152 f
  float* hstart = hend   + (size_t)B_ * NC * D_ * N_;   // 2,097,152 f
  float* sdsum  = hstart + (size_t)B_ * NC * D_ * N_;   //   131,072 f
  unsigned short* xb    = (unsigned short*)(sdsum + (size_t)B_ * NC * D_);
  unsigned short* WBC   = xb    + (size_t)BS_ * D_;     // 32,768 u16
  unsigned short* wdtb  = WBC   + (size_t)32 * D_;      // 65,536 u16
  unsigned short* wdtwT = wdtb  + (size_t)D_ * R_;      // 65,536 u16
  unsigned short* weff  = wdtwT + (size_t)D_ * R_;      // 1,048,576 u16
  unsigned short* wob   = weff  + (size_t)D_ * D_;      // 1,048,576 u16
  unsigned short* ybf   = wob   + (size_t)D_ * D_;      // 4,194,304 u16

  k_castall<<<dim3(5280), dim3(256), 0, stream>>>(x, W_B, W_C, W_dt, W_out, W_dtw,
                                                  xb, WBC, wdtb, wob, wdtwT);
  k_weff<<<dim3(8, 8), dim3(256), 0, stream>>>(wdtb, wdtwT, weff);
  k_deltaBC<<<dim3(BS_ / 128, 17), dim3(256), 0, stream>>>(xb, weff, WBC, b_dt,
                                                           delta, Bm, Cm);
  k_scan1<<<dim3(B_ * NC * (D_ / 64)), dim3(256), 0, stream>>>(x, delta, Bm, A_log,
                                                               sdsum, hend);
  k_scan2<<<dim3(B_ * D_ * N_ / 256), dim3(256), 0, stream>>>(sdsum, hend, A_log, hstart);
  k_scan3<<<dim3(B_ * NC * (D_ / 64)), dim3(256), 0, stream>>>(x, delta, Bm, Cm,
                                                               A_log, hstart, Dp, ypre);
  k_ln<<<dim3(BS_), dim3(256), 0, stream>>>(ypre, ln_g, ln_b, ybf);
  k_out<<<dim3(BS_ / 128, D_ / 64), dim3(256), 0, stream>>>(ybf, wob, out);
}